// Round 14
// baseline (900.827 us; speedup 1.0000x reference)
//
#include <hip/hip_runtime.h>

#define A_ 8
#define B_ 64
#define S_ 128
#define E_ 512
#define H_ 512

typedef float f32x4 __attribute__((ext_vector_type(4)));
typedef short s16x8 __attribute__((ext_vector_type(8)));

__device__ __forceinline__ float sigm(float v)   { return 1.f / (1.f + __expf(-v)); }
__device__ __forceinline__ float tanh_f(float v) { return 2.f / (1.f + __expf(-2.f * v)) - 1.f; }

__device__ __forceinline__ unsigned short f2bf(float f) {
  unsigned u = __builtin_bit_cast(unsigned, f);
  u += 0x7fffu + ((u >> 16) & 1u);
  return (unsigned short)(u >> 16);
}
__device__ __forceinline__ float bf2f(unsigned short b) {
  return __builtin_bit_cast(float, ((unsigned)b) << 16);
}

union U2 { unsigned long long u[2]; s16x8 v; };
union PK { uint4 u; unsigned short h[8]; };
union PH { s16x8 v; unsigned short h[8]; };

// ---------------------------------------------------------------------------
// Phase 0: one-pass W_in -> bf16 MFMA-fragment conversion.
// wfrag[((a*3+g)*16 + kt)*8 + nt][rem(256)] of s16x8; rem = cs*64 + lane,
// fragment (cs,lane): col = nt*64 + cs*16 + (lane&15), k = kt*32+(lane>>4)*8+j.
// Done ONCE instead of per-(b)-WG (64x) in proj. 12.6 MB.
// ---------------------------------------------------------------------------
__global__ __launch_bounds__(256) void gru_wconv(
    const float* __restrict__ wri, const float* __restrict__ wzi,
    const float* __restrict__ wni, s16x8* __restrict__ wfrag)
{
  const int bid = blockIdx.x;      // (a*3+g)*16 + kt
  const int kt  = bid & 15;
  const int ag  = bid >> 4;
  const int g   = ag % 3;
  const int a   = ag / 3;
  const float* W = g == 0 ? wri : g == 1 ? wzi : wni;
  const int t  = threadIdx.x;
  const int l  = t & 63;
  const int cs = (t >> 6) & 3;
  const int colbase = cs * 16 + (l & 15);
  const int kb = kt * 32 + (l >> 4) * 8;
  const float* wp0 = W + (size_t)(a * E_ + kb) * H_;
#pragma unroll
  for (int nt = 0; nt < 8; ++nt) {
    const float* wp = wp0 + nt * 64 + colbase;
    PH pb;
#pragma unroll
    for (int j = 0; j < 8; ++j) pb.h[j] = f2bf(wp[(size_t)j * H_]);
    wfrag[((size_t)bid * 8 + nt) * 256 + t] = pb.v;
  }
}

// ---------------------------------------------------------------------------
// Phase 1: input projections, 3 gates fused; B-operand read from wfrag
// (coalesced 16B copies, no gather / no f2bf in the hot loop).
//   gates r,z -> packed bf16 pair in xprz[a][s][b][h]; gate n -> f32 xn.
// ---------------------------------------------------------------------------
__global__ __launch_bounds__(256, 2) void gru_proj(
    const float* __restrict__ x,
    const s16x8* __restrict__ wfrag,
    const float* __restrict__ bri, const float* __restrict__ bzi, const float* __restrict__ bni,
    const float* __restrict__ brh, const float* __restrict__ bzh,
    unsigned* __restrict__ xprz, float* __restrict__ xn_arr)
{
  const int ntI  = blockIdx.x;        // n-tile (XCD-sticky W)
  const int n0   = ntI * 64;
  const int b    = blockIdx.y;
  const int a    = blockIdx.z;
  const int tid  = threadIdx.x;
  const int lane = tid & 63;
  const int wid  = tid >> 6;
  const int l15  = lane & 15;
  const int l4   = lane >> 4;

  const float* xp = x + (size_t)(a * B_ + b) * S_ * E_;
  const s16x8* wfA = wfrag + ((size_t)a * 3) * 16 * 8 * 256;

  __shared__ short Af[4096];   // 128 s x 32 k = 8 KB
  __shared__ short Bf[6144];   // 3 gates x 4 coltiles x 64 lanes x 8 = 12 KB

  f32x4 acc[3][2][4];
#pragma unroll
  for (int g = 0; g < 3; ++g)
#pragma unroll
    for (int m = 0; m < 2; ++m)
#pragma unroll
      for (int c = 0; c < 4; ++c) acc[g][m][c] = (f32x4){0.f, 0.f, 0.f, 0.f};

  const int am = tid >> 1;
  const int ah = tid & 1;

  for (int kt = 0; kt < E_; kt += 32) {
    const int kti = kt >> 5;
    // ---- stage A once (x rows, 64B/thread, cvt to bf16 fragments) ----
    const float* ap = xp + (size_t)am * E_ + kt + ah * 16;
    float4 a0 = *(const float4*)(ap);
    float4 a1 = *(const float4*)(ap + 4);
    float4 a2 = *(const float4*)(ap + 8);
    float4 a3 = *(const float4*)(ap + 12);
    PH pa0, pa1;
    pa0.h[0]=f2bf(a0.x); pa0.h[1]=f2bf(a0.y); pa0.h[2]=f2bf(a0.z); pa0.h[3]=f2bf(a0.w);
    pa0.h[4]=f2bf(a1.x); pa0.h[5]=f2bf(a1.y); pa0.h[6]=f2bf(a1.z); pa0.h[7]=f2bf(a1.w);
    pa1.h[0]=f2bf(a2.x); pa1.h[1]=f2bf(a2.y); pa1.h[2]=f2bf(a2.z); pa1.h[3]=f2bf(a2.w);
    pa1.h[4]=f2bf(a3.x); pa1.h[5]=f2bf(a3.y); pa1.h[6]=f2bf(a3.z); pa1.h[7]=f2bf(a3.w);
    int au = (am >> 4) * 64 + (ah * 2) * 16 + (am & 15);
    ((s16x8*)Af)[au]      = pa0.v;
    ((s16x8*)Af)[au + 16] = pa1.v;

    // ---- stage B: straight coalesced copies from wfrag ----
#pragma unroll
    for (int ii = 0; ii < 3; ++ii) {
      int idx = tid + ii * 256;           // g*256 + rem
      int g   = idx >> 8;
      int rem = idx & 255;
      ((s16x8*)Bf)[idx] = wfA[(((size_t)g * 16 + kti) * 8 + ntI) * 256 + rem];
    }
    __syncthreads();

    s16x8 av0 = ((s16x8*)Af)[(wid * 2 + 0) * 64 + lane];
    s16x8 av1 = ((s16x8*)Af)[(wid * 2 + 1) * 64 + lane];
#pragma unroll
    for (int g = 0; g < 3; ++g)
#pragma unroll
      for (int cs = 0; cs < 4; ++cs) {
        s16x8 bv = ((s16x8*)Bf)[g * 256 + cs * 64 + lane];
        acc[g][0][cs] = __builtin_amdgcn_mfma_f32_16x16x32_bf16(av0, bv, acc[g][0][cs], 0, 0, 0);
        acc[g][1][cs] = __builtin_amdgcn_mfma_f32_16x16x32_bf16(av1, bv, acc[g][1][cs], 0, 0, 0);
      }
    __syncthreads();
  }

  // ---- epilogue: bias fold + packed stores ----
#pragma unroll
  for (int cs = 0; cs < 4; ++cs) {
    int col = n0 + cs * 16 + l15;
    float br = bri[a * H_ + col] + brh[a * H_ + col];
    float bz = bzi[a * H_ + col] + bzh[a * H_ + col];
    float bn = bni[a * H_ + col];
#pragma unroll
    for (int m = 0; m < 2; ++m) {
#pragma unroll
      for (int i = 0; i < 4; ++i) {
        int srow = wid * 32 + m * 16 + l4 * 4 + i;   // = s
        size_t base = ((size_t)(a * S_ + srow) * B_ + b) * H_ + col;
        float rv = acc[0][m][cs][i] + br;
        float zv = acc[1][m][cs][i] + bz;
        float nv = acc[2][m][cs][i] + bn;
        xprz[base]   = (unsigned)f2bf(rv) | ((unsigned)f2bf(zv) << 16);
        xn_arr[base] = nv;
      }
    }
  }
}

// ---------------------------------------------------------------------------
// Phase 2: persistent scan, r9 structure + TWO-PHASE pipelined h acquisition.
// 16 groups G=wg&15 (a=G>>1, hf=G&1), 16 WGs/group (slice=wg>>4, 32 cols),
// wave = 16x16 C-tile. Chunk kk <-> producer slice kk. Bottom of step s:
// poll flags 0-7 -> issue hh[0..7] loads -> poll flags 8-15 -> issue
// hh[8..15] loads (phase-A load latency hides under phase-B poll). MFMA at
// top of s+1 consumes hh (compiler waitcnt). Safety = r9 invariant: loads
// strictly after producer flags; reader drains own loads via its next-step
// __syncthreads before flagging; writer overwrites only after poll target
// s+2. Relaxed agent atomics only.
// ---------------------------------------------------------------------------
__global__ __launch_bounds__(256, 1) void gru_scan(
    const unsigned* __restrict__ xprz, const float* __restrict__ xn_arr,
    const float* __restrict__ wrh, const float* __restrict__ wzh, const float* __restrict__ wnh,
    const float* __restrict__ bnh,
    float* __restrict__ out, float* __restrict__ hlast,
    unsigned short* __restrict__ hbuf0, unsigned short* __restrict__ hbuf1,
    int* __restrict__ flags)
{
  __shared__ uint4 wflat[6144];   // [gate(3)][kk(16)][nt(2)][lane(64)] = 96 KB

  const int wg    = blockIdx.x;
  const int G     = wg & 15;
  const int a     = G >> 1;
  const int hf    = G & 1;
  const int slice = wg >> 4;
  const int tid   = threadIdx.x;
  const int lane  = tid & 63;
  const int w     = tid >> 6;
  const int l15   = lane & 15;
  const int l4    = lane >> 4;
  const int mt    = w & 1;
  const int nt    = w >> 1;

  for (int idx = tid; idx < 6144; idx += 256) {
    int gate = idx >> 11;
    int rem  = idx & 2047;
    int kk   = rem >> 7;
    int rem2 = rem & 127;
    int nt_  = rem2 >> 6;
    int l    = rem2 & 63;
    int col   = slice * 32 + nt_ * 16 + (l & 15);
    int kbase = kk * 32 + (l >> 4) * 8;
    const float* W = gate == 0 ? wrh : gate == 1 ? wzh : wnh;
    const float* wp = W + ((size_t)(a * H_ + kbase)) * H_ + col;
    PK pk;
#pragma unroll
    for (int j = 0; j < 8; ++j) pk.h[j] = f2bf(wp[(size_t)j * H_]);
    wflat[idx] = pk.u;
  }
  __syncthreads();

  const int nc    = slice * 32 + nt * 16 + l15;
  const float vbnh = bnh[a * H_ + nc];
  const int halfb = (a * 2 + hf) * 16384;
  const int hbase = halfb + l4 * 256 + (mt * 16 + l15) * 8;  // + kk*1024
  int* flagsG = flags + G * (16 * 32);

  float hold[4] = {0.f, 0.f, 0.f, 0.f};
  float xr_[4], xz_[4], xn_[4];

#pragma unroll
  for (int i = 0; i < 4; ++i) {
    int b = hf * 32 + mt * 16 + l4 * 4 + i;
    size_t xo = ((size_t)(a * S_ + 0) * B_ + b) * H_ + nc;
    unsigned prz = xprz[xo];
    xr_[i] = bf2f((unsigned short)(prz & 0xffff));
    xz_[i] = bf2f((unsigned short)(prz >> 16));
    xn_[i] = xn_arr[xo];
  }

  const f32x4 zero4 = {0.f, 0.f, 0.f, 0.f};

  U2 hh[16];
#pragma unroll
  for (int kk = 0; kk < 16; ++kk) { hh[kk].u[0] = 0ull; hh[kk].u[1] = 0ull; }

  for (int s = 0; s < S_; ++s) {
    unsigned short* hcur = (s & 1) ? hbuf1 : hbuf0;

    // MFMA on hh (h_{s-1}; zeros at s=0)
    f32x4 aR = zero4, aZ = zero4, aHN = zero4;
#pragma unroll
    for (int kk = 0; kk < 16; ++kk) {
      s16x8 bR = __builtin_bit_cast(s16x8, wflat[kk * 128        + nt * 64 + lane]);
      s16x8 bZ = __builtin_bit_cast(s16x8, wflat[2048 + kk * 128 + nt * 64 + lane]);
      s16x8 bN = __builtin_bit_cast(s16x8, wflat[4096 + kk * 128 + nt * 64 + lane]);
      aR  = __builtin_amdgcn_mfma_f32_16x16x32_bf16(hh[kk].v, bR, aR, 0, 0, 0);
      aZ  = __builtin_amdgcn_mfma_f32_16x16x32_bf16(hh[kk].v, bZ, aZ, 0, 0, 0);
      aHN = __builtin_amdgcn_mfma_f32_16x16x32_bf16(hh[kk].v, bN, aHN, 0, 0, 0);
    }

    float hn4[4];
#pragma unroll
    for (int i = 0; i < 4; ++i) {
      float rg = sigm(xr_[i] + aR[i]);
      float zg = sigm(xz_[i] + aZ[i]);
      float ng = tanh_f(xn_[i] + rg * (aHN[i] + vbnh));
      hn4[i] = (1.f - zg) * ng + zg * hold[i];
      hold[i] = hn4[i];
    }

    // store h_s (packed bf16 pairs)
#pragma unroll
    for (int i = 0; i < 4; ++i) {
      int r = mt * 16 + l4 * 4 + i;
      unsigned short nb = f2bf(hn4[i]);
      unsigned other = __shfl_xor((unsigned)nb, 1);
      if ((lane & 1) == 0) {
        unsigned val = (unsigned)nb | (other << 16);
        __hip_atomic_store((unsigned*)(hcur + halfb + (nc >> 3) * 256 + r * 8 + (nc & 6)),
                           val, __ATOMIC_RELAXED, __HIP_MEMORY_SCOPE_AGENT);
      }
    }
    __syncthreads();   // drains vmcnt: h stores acked, prior-step h loads done
    asm volatile("" ::: "memory");
    if (tid == 0)
      __hip_atomic_store(flagsG + slice * 32, s + 1,
                         __ATOMIC_RELAXED, __HIP_MEMORY_SCOPE_AGENT);

    // off the critical path: out stores + x prefetch
#pragma unroll
    for (int i = 0; i < 4; ++i) {
      int b = hf * 32 + mt * 16 + l4 * 4 + i;
      out[((size_t)(a * B_ + b) * S_ + s) * H_ + nc] = hn4[i];
    }
    if (s == S_ - 1) {
#pragma unroll
      for (int i = 0; i < 4; ++i) {
        int b = hf * 32 + mt * 16 + l4 * 4 + i;
        hlast[(size_t)(a * B_ + b) * H_ + nc] = hn4[i];
      }
    } else {
#pragma unroll
      for (int i = 0; i < 4; ++i) {
        int b = hf * 32 + mt * 16 + l4 * 4 + i;
        size_t xo = ((size_t)(a * S_ + (s + 1)) * B_ + b) * H_ + nc;
        unsigned prz = xprz[xo];
        xr_[i] = bf2f((unsigned short)(prz & 0xffff));
        xz_[i] = bf2f((unsigned short)(prz >> 16));
        xn_[i] = xn_arr[xo];
      }
      const int target = s + 1;
      // phase A: producers 0..7 ready -> issue their chunks
      for (;;) {
        int v = __hip_atomic_load(flagsG + (lane & 7) * 32,
                                  __ATOMIC_RELAXED, __HIP_MEMORY_SCOPE_AGENT);
        if (__all(v >= target)) break;
      }
      asm volatile("" ::: "memory");
#pragma unroll
      for (int kk = 0; kk < 8; ++kk) {
        const unsigned long long* p =
            (const unsigned long long*)(hcur + hbase + kk * 1024);
        hh[kk].u[0] = __hip_atomic_load(p,     __ATOMIC_RELAXED, __HIP_MEMORY_SCOPE_AGENT);
        hh[kk].u[1] = __hip_atomic_load(p + 1, __ATOMIC_RELAXED, __HIP_MEMORY_SCOPE_AGENT);
      }
      // phase B: producers 8..15 (phase-A load latency hides under this poll)
      for (;;) {
        int v = __hip_atomic_load(flagsG + ((lane & 7) + 8) * 32,
                                  __ATOMIC_RELAXED, __HIP_MEMORY_SCOPE_AGENT);
        if (__all(v >= target)) break;
      }
      asm volatile("" ::: "memory");
#pragma unroll
      for (int kk = 8; kk < 16; ++kk) {
        const unsigned long long* p =
            (const unsigned long long*)(hcur + hbase + kk * 1024);
        hh[kk].u[0] = __hip_atomic_load(p,     __ATOMIC_RELAXED, __HIP_MEMORY_SCOPE_AGENT);
        hh[kk].u[1] = __hip_atomic_load(p + 1, __ATOMIC_RELAXED, __HIP_MEMORY_SCOPE_AGENT);
      }
    }
  }
}

// ---------------------------------------------------------------------------
// Fallback: round-2 persistent kernel (needs only ~1 MB ws).
// ---------------------------------------------------------------------------
__global__ __launch_bounds__(256, 1) void gru_persist(
    const float* __restrict__ x,
    const float* __restrict__ wri, const float* __restrict__ wzi, const float* __restrict__ wni,
    const float* __restrict__ wrh, const float* __restrict__ wzh, const float* __restrict__ wnh,
    const float* __restrict__ bri, const float* __restrict__ bzi, const float* __restrict__ bni,
    const float* __restrict__ brh, const float* __restrict__ bzh, const float* __restrict__ bnh,
    float* __restrict__ out, float* __restrict__ hlast,
    unsigned short* __restrict__ hbuf0, unsigned short* __restrict__ hbuf1,
    int* __restrict__ flags)
{
  __shared__ uint4 wflat[6144];
  const int wg = blockIdx.x, a = wg >> 5, slice = wg & 31, n0 = slice << 4;
  const int tid = threadIdx.x, lane = tid & 63, wid = tid >> 6;
  const int l15 = lane & 15, l4 = lane >> 4, b0w = wid << 4;

  for (int idx = tid; idx < 6144; idx += 256) {
    int set = idx / 3072, rem = idx - set * 3072, gate = rem >> 10;
    int rem2 = rem & 1023, kk = rem2 >> 6, l = rem2 & 63;
    int c = l & 15, kbase = kk * 32 + (l >> 4) * 8;
    const float* W = (set == 0) ? (gate == 0 ? wri : gate == 1 ? wzi : wni)
                                : (gate == 0 ? wrh : gate == 1 ? wzh : wnh);
    const float* wp = W + ((size_t)(a * 512 + kbase)) * 512 + n0 + c;
    PK pk;
#pragma unroll
    for (int j = 0; j < 8; ++j) pk.h[j] = f2bf(wp[(size_t)j * 512]);
    wflat[idx] = pk.u;
  }
  __syncthreads();

  const int nc = n0 + l15;
  const float vbri = bri[a*512+nc], vbzi = bzi[a*512+nc], vbni = bni[a*512+nc];
  const float vbrh = brh[a*512+nc], vbzh = bzh[a*512+nc], vbnh = bnh[a*512+nc];
  const float* xrow = x + (size_t)(a * 64 + b0w + l15) * 65536 + l4 * 8;
  const int hbase = ((a * 64 + l4) * 64 + b0w + l15) * 8;
  int* flagsA = flags + a * 64;
  const f32x4 zero4 = {0.f, 0.f, 0.f, 0.f};
  f32x4 aR, aZ, aXN, aHN;

  auto xpart = [&](int sv) {
    const float* xp = xrow + (size_t)sv * 512;
    aR = zero4; aZ = zero4; aXN = zero4;
#pragma unroll
    for (int kk = 0; kk < 16; ++kk) {
      float4 x0 = *reinterpret_cast<const float4*>(xp + kk * 32);
      float4 x1 = *reinterpret_cast<const float4*>(xp + kk * 32 + 4);
      PH af;
      af.h[0]=f2bf(x0.x); af.h[1]=f2bf(x0.y); af.h[2]=f2bf(x0.z); af.h[3]=f2bf(x0.w);
      af.h[4]=f2bf(x1.x); af.h[5]=f2bf(x1.y); af.h[6]=f2bf(x1.z); af.h[7]=f2bf(x1.w);
      s16x8 bR = __builtin_bit_cast(s16x8, wflat[(kk)*64+lane]);
      s16x8 bZ = __builtin_bit_cast(s16x8, wflat[(16+kk)*64+lane]);
      s16x8 bN = __builtin_bit_cast(s16x8, wflat[(32+kk)*64+lane]);
      aR  = __builtin_amdgcn_mfma_f32_16x16x32_bf16(af.v, bR, aR, 0,0,0);
      aZ  = __builtin_amdgcn_mfma_f32_16x16x32_bf16(af.v, bZ, aZ, 0,0,0);
      aXN = __builtin_amdgcn_mfma_f32_16x16x32_bf16(af.v, bN, aXN, 0,0,0);
    }
  };

  xpart(0);
  for (int s = 0; s < S_; ++s) {
    const unsigned short* hprev = (s & 1) ? hbuf0 : hbuf1;
    unsigned short*       hcur  = (s & 1) ? hbuf1 : hbuf0;
    aHN = zero4;
#pragma unroll
    for (int kk = 0; kk < 16; ++kk) {
      unsigned long long* p = (unsigned long long*)(hprev + hbase + kk * 2048);
      U2 uu;
      uu.u[0] = __hip_atomic_load(p,   __ATOMIC_RELAXED, __HIP_MEMORY_SCOPE_AGENT);
      uu.u[1] = __hip_atomic_load(p+1, __ATOMIC_RELAXED, __HIP_MEMORY_SCOPE_AGENT);
      s16x8 bR = __builtin_bit_cast(s16x8, wflat[(48+kk)*64+lane]);
      s16x8 bZ = __builtin_bit_cast(s16x8, wflat[(64+kk)*64+lane]);
      s16x8 bN = __builtin_bit_cast(s16x8, wflat[(80+kk)*64+lane]);
      aR  = __builtin_amdgcn_mfma_f32_16x16x32_bf16(uu.v, bR, aR, 0,0,0);
      aZ  = __builtin_amdgcn_mfma_f32_16x16x32_bf16(uu.v, bZ, aZ, 0,0,0);
      aHN = __builtin_amdgcn_mfma_f32_16x16x32_bf16(uu.v, bN, aHN, 0,0,0);
    }
#pragma unroll
    for (int i = 0; i < 4; ++i) {
      int r = b0w + l4 * 4 + i;
      unsigned* hop = (unsigned*)(hprev + ((a*64 + (nc>>3))*64 + r)*8 + (nc&6));
      unsigned pair = __hip_atomic_load(hop, __ATOMIC_RELAXED, __HIP_MEMORY_SCOPE_AGENT);
      float hold = bf2f((nc & 1) ? (unsigned short)(pair >> 16) : (unsigned short)(pair & 0xffff));
      float rg = sigm(aR[i] + vbri + vbrh);
      float zg = sigm(aZ[i] + vbzi + vbzh);
      float ng = tanh_f(aXN[i] + vbni + rg * (aHN[i] + vbnh));
      float hnew = (1.f - zg) * ng + zg * hold;
      out[((size_t)(a*64 + r)*128 + s)*512 + nc] = hnew;
      if (s == S_ - 1) hlast[(size_t)(a*64 + r)*512 + nc] = hnew;
      unsigned short nb = f2bf(hnew);
      unsigned other = __shfl_xor((unsigned)nb, 1);
      if ((lane & 1) == 0) {
        unsigned val = (unsigned)nb | (other << 16);
        __hip_atomic_store((unsigned*)(hcur + ((a*64 + (nc>>3))*64 + r)*8 + (nc&6)),
                           val, __ATOMIC_RELAXED, __HIP_MEMORY_SCOPE_AGENT);
      }
    }
    __syncthreads();
    if (tid == 0)
      __hip_atomic_store(flagsA + slice, s + 1, __ATOMIC_RELEASE, __HIP_MEMORY_SCOPE_AGENT);
    if (s < S_ - 1) {
      xpart(s + 1);
      const int target = s + 1;
      for (;;) {
        int v = __hip_atomic_load(flagsA + (lane & 31), __ATOMIC_ACQUIRE, __HIP_MEMORY_SCOPE_AGENT);
        if (__all(v >= target)) break;
        __builtin_amdgcn_s_sleep(1);
      }
    }
  }
}

extern "C" void kernel_launch(void* const* d_in, const int* in_sizes, int n_in,
                              void* d_out, int out_size, void* d_ws, size_t ws_size,
                              hipStream_t stream)
{
  const float* x   = (const float*)d_in[0];
  const float* wri = (const float*)d_in[1];
  const float* wzi = (const float*)d_in[2];
  const float* wni = (const float*)d_in[3];
  const float* wrh = (const float*)d_in[4];
  const float* wzh = (const float*)d_in[5];
  const float* wnh = (const float*)d_in[6];
  const float* bri = (const float*)d_in[7];
  const float* bzi = (const float*)d_in[8];
  const float* bni = (const float*)d_in[9];
  const float* brh = (const float*)d_in[10];
  const float* bzh = (const float*)d_in[11];
  const float* bnh = (const float*)d_in[12];

  float* out   = (float*)d_out;                    // (A,B,S,H)
  float* hlast = out + (size_t)A_ * B_ * S_ * H_;  // (A,B,H)

  const size_t XPRZ    = (size_t)A_ * S_ * B_ * H_;            // u32 / f32 elems
  const size_t WFRAG   = (size_t)384 * 8 * 256;                // s16x8 elems
  const size_t HBUF    = (size_t)A_ * 64 * 64 * 8;             // bf16 elems
  const size_t FLAGS_B = (size_t)16 * 16 * 32 * sizeof(int);   // 32 KB
  const size_t need_new = XPRZ * 8 + WFRAG * 16 + HBUF * 4 + FLAGS_B;
  const size_t need_old = HBUF * 4 + 2048;

  if (ws_size >= need_new) {
    unsigned* xprz = (unsigned*)d_ws;
    float* xn_arr  = (float*)((char*)d_ws + XPRZ * 4);
    s16x8* wfrag   = (s16x8*)((char*)d_ws + XPRZ * 8);
    unsigned short* hbuf0 = (unsigned short*)((char*)d_ws + XPRZ * 8 + WFRAG * 16);
    unsigned short* hbuf1 = hbuf0 + HBUF;
    int* flags = (int*)(hbuf1 + HBUF);
    hipMemsetAsync(hbuf0, 0, HBUF * 4 + FLAGS_B, stream);
    gru_wconv<<<384, 256, 0, stream>>>(wri, wzi, wni, wfrag);
    gru_proj<<<dim3(8, 64, 8), 256, 0, stream>>>(x, wfrag,
                                                 bri, bzi, bni, brh, bzh,
                                                 xprz, xn_arr);
    gru_scan<<<256, 256, 0, stream>>>(xprz, xn_arr, wrh, wzh, wnh, bnh,
                                      out, hlast, hbuf0, hbuf1, flags);
  } else if (ws_size >= need_old) {
    unsigned short* hbuf0 = (unsigned short*)d_ws;
    unsigned short* hbuf1 = hbuf0 + HBUF;
    int* flags = (int*)(hbuf1 + HBUF);
    hipMemsetAsync(d_ws, 0, need_old, stream);
    gru_persist<<<256, 256, 0, stream>>>(x, wri, wzi, wni, wrh, wzh, wnh,
                                         bri, bzi, bni, brh, bzh, bnh,
                                         out, hlast, hbuf0, hbuf1, flags);
  }
}

// Round 15
// 753.400 us; speedup vs baseline: 1.1957x; 1.1957x over previous
//
#include <hip/hip_runtime.h>

#define A_ 8
#define B_ 64
#define S_ 128
#define E_ 512
#define H_ 512

typedef float f32x4 __attribute__((ext_vector_type(4)));
typedef short s16x8 __attribute__((ext_vector_type(8)));

__device__ __forceinline__ float sigm(float v)   { return 1.f / (1.f + __expf(-v)); }
__device__ __forceinline__ float tanh_f(float v) { return 2.f / (1.f + __expf(-2.f * v)) - 1.f; }

__device__ __forceinline__ unsigned short f2bf(float f) {
  unsigned u = __builtin_bit_cast(unsigned, f);
  u += 0x7fffu + ((u >> 16) & 1u);
  return (unsigned short)(u >> 16);
}
__device__ __forceinline__ float bf2f(unsigned short b) {
  return __builtin_bit_cast(float, ((unsigned)b) << 16);
}

union U2 { unsigned long long u[2]; s16x8 v; };
union PK { uint4 u; unsigned short h[8]; };
union PH { s16x8 v; unsigned short h[8]; };

// ---------------------------------------------------------------------------
// Phase 1: input projections, 3 gates fused per WG (round-12 proven config).
// Grid (b=64, ntile64=8, a=8), 256 thr. Tile 128(s) x 64(n), K=512.
// A-tile (x) staged + f2bf ONCE per k-tile, reused by all 3 gate B-matrices.
//   gates r,z -> packed bf16 pair in xprz[a][s][b][h] (u32: lo=r, hi=z)
//   gate  n   -> f32 xn[a][s][b][h]
// ---------------------------------------------------------------------------
__global__ __launch_bounds__(256, 2) void gru_proj(
    const float* __restrict__ x,
    const float* __restrict__ wri, const float* __restrict__ wzi, const float* __restrict__ wni,
    const float* __restrict__ bri, const float* __restrict__ bzi, const float* __restrict__ bni,
    const float* __restrict__ brh, const float* __restrict__ bzh,
    unsigned* __restrict__ xprz, float* __restrict__ xn_arr)
{
  const int b    = blockIdx.x;        // 0..63
  const int n0   = blockIdx.y * 64;   // col base
  const int a    = blockIdx.z;
  const int tid  = threadIdx.x;
  const int lane = tid & 63;
  const int wid  = tid >> 6;
  const int l15  = lane & 15;
  const int l4   = lane >> 4;

  const float* xp = x + (size_t)(a * B_ + b) * S_ * E_;

  __shared__ short Af[4096];   // 128 s x 32 k = 8 KB
  __shared__ short Bf[6144];   // 3 gates x 4 coltiles x 64 lanes x 8 = 12 KB

  f32x4 acc[3][2][4];          // [gate][mtile][coltile]
#pragma unroll
  for (int g = 0; g < 3; ++g)
#pragma unroll
    for (int m = 0; m < 2; ++m)
#pragma unroll
      for (int c = 0; c < 4; ++c) acc[g][m][c] = (f32x4){0.f, 0.f, 0.f, 0.f};

  const int am = tid >> 1;     // A row (= s), 0..127
  const int ah = tid & 1;      // A k-half (16 elems)

  for (int kt = 0; kt < E_; kt += 32) {
    // ---- stage A once (x rows, 64B/thread, cvt to bf16 fragments) ----
    const float* ap = xp + (size_t)am * E_ + kt + ah * 16;
    float4 a0 = *(const float4*)(ap);
    float4 a1 = *(const float4*)(ap + 4);
    float4 a2 = *(const float4*)(ap + 8);
    float4 a3 = *(const float4*)(ap + 12);
    PH pa0, pa1;
    pa0.h[0]=f2bf(a0.x); pa0.h[1]=f2bf(a0.y); pa0.h[2]=f2bf(a0.z); pa0.h[3]=f2bf(a0.w);
    pa0.h[4]=f2bf(a1.x); pa0.h[5]=f2bf(a1.y); pa0.h[6]=f2bf(a1.z); pa0.h[7]=f2bf(a1.w);
    pa1.h[0]=f2bf(a2.x); pa1.h[1]=f2bf(a2.y); pa1.h[2]=f2bf(a2.z); pa1.h[3]=f2bf(a2.w);
    pa1.h[4]=f2bf(a3.x); pa1.h[5]=f2bf(a3.y); pa1.h[6]=f2bf(a3.z); pa1.h[7]=f2bf(a3.w);
    int au = (am >> 4) * 64 + (ah * 2) * 16 + (am & 15);
    ((s16x8*)Af)[au]      = pa0.v;
    ((s16x8*)Af)[au + 16] = pa1.v;

    // ---- stage B: 3 gates x 64 cols x 32 k = 768 frags, 3/thread ----
#pragma unroll
    for (int ii = 0; ii < 3; ++ii) {
      int idx  = tid + ii * 256;        // 0..767 = gate*256 + cs*64 + l
      int gate = idx >> 8;
      int rem  = idx & 255;
      int l    = rem & 63;
      int col  = n0 + ((rem >> 6) << 4) + (l & 15);
      int kb   = kt + (l >> 4) * 8;
      const float* W = gate == 0 ? wri : gate == 1 ? wzi : wni;
      const float* wp2 = W + (size_t)(a * E_ + kb) * H_ + col;
      PH pb;
#pragma unroll
      for (int j = 0; j < 8; ++j) pb.h[j] = f2bf(wp2[(size_t)j * H_]);
      ((s16x8*)Bf)[idx] = pb.v;
    }
    __syncthreads();

    s16x8 av0 = ((s16x8*)Af)[(wid * 2 + 0) * 64 + lane];
    s16x8 av1 = ((s16x8*)Af)[(wid * 2 + 1) * 64 + lane];
#pragma unroll
    for (int g = 0; g < 3; ++g)
#pragma unroll
      for (int cs = 0; cs < 4; ++cs) {
        s16x8 bv = ((s16x8*)Bf)[g * 256 + cs * 64 + lane];
        acc[g][0][cs] = __builtin_amdgcn_mfma_f32_16x16x32_bf16(av0, bv, acc[g][0][cs], 0, 0, 0);
        acc[g][1][cs] = __builtin_amdgcn_mfma_f32_16x16x32_bf16(av1, bv, acc[g][1][cs], 0, 0, 0);
      }
    __syncthreads();
  }

  // ---- epilogue: bias fold + packed stores ----
#pragma unroll
  for (int cs = 0; cs < 4; ++cs) {
    int col = n0 + cs * 16 + l15;
    float br = bri[a * H_ + col] + brh[a * H_ + col];
    float bz = bzi[a * H_ + col] + bzh[a * H_ + col];
    float bn = bni[a * H_ + col];
#pragma unroll
    for (int m = 0; m < 2; ++m) {
#pragma unroll
      for (int i = 0; i < 4; ++i) {
        int srow = wid * 32 + m * 16 + l4 * 4 + i;   // = s
        size_t base = ((size_t)(a * S_ + srow) * B_ + b) * H_ + col;
        float rv = acc[0][m][cs][i] + br;
        float zv = acc[1][m][cs][i] + bz;
        float nv = acc[2][m][cs][i] + bn;
        xprz[base]   = (unsigned)f2bf(rv) | ((unsigned)f2bf(zv) << 16);
        xn_arr[base] = nv;
      }
    }
  }
}

// ---------------------------------------------------------------------------
// Phase 2: persistent scan — round 9/12 proven structure (529-544 us).
// 16 groups G=wg&15 (a=G>>1, b-half hf=G&1), 16 WGs/group (slice=wg>>4,
// 32 cols each), wave = 16x16 C-tile. Relaxed-only sync; per-WG flag after
// vmcnt-draining __syncthreads; all waves poll 16 flags once, fall through.
// ---------------------------------------------------------------------------
__global__ __launch_bounds__(256, 1) void gru_scan(
    const unsigned* __restrict__ xprz, const float* __restrict__ xn_arr,
    const float* __restrict__ wrh, const float* __restrict__ wzh, const float* __restrict__ wnh,
    const float* __restrict__ bnh,
    float* __restrict__ out, float* __restrict__ hlast,
    unsigned short* __restrict__ hbuf0, unsigned short* __restrict__ hbuf1,
    int* __restrict__ flags)
{
  __shared__ uint4 wflat[6144];   // [gate(3)][kk(16)][nt(2)][lane(64)] = 96 KB

  const int wg    = blockIdx.x;
  const int G     = wg & 15;
  const int a     = G >> 1;
  const int hf    = G & 1;
  const int slice = wg >> 4;
  const int tid   = threadIdx.x;
  const int lane  = tid & 63;
  const int w     = tid >> 6;
  const int l15   = lane & 15;
  const int l4    = lane >> 4;
  const int mt    = w & 1;
  const int nt    = w >> 1;

  for (int idx = tid; idx < 6144; idx += 256) {
    int gate = idx >> 11;
    int rem  = idx & 2047;
    int kk   = rem >> 7;
    int rem2 = rem & 127;
    int nt_  = rem2 >> 6;
    int l    = rem2 & 63;
    int col   = slice * 32 + nt_ * 16 + (l & 15);
    int kbase = kk * 32 + (l >> 4) * 8;
    const float* W = gate == 0 ? wrh : gate == 1 ? wzh : wnh;
    const float* wp = W + ((size_t)(a * H_ + kbase)) * H_ + col;
    PK pk;
#pragma unroll
    for (int j = 0; j < 8; ++j) pk.h[j] = f2bf(wp[(size_t)j * H_]);
    wflat[idx] = pk.u;
  }
  __syncthreads();

  const int nc    = slice * 32 + nt * 16 + l15;
  const float vbnh = bnh[a * H_ + nc];
  const int halfb = (a * 2 + hf) * 16384;
  const int hbase = halfb + l4 * 256 + (mt * 16 + l15) * 8;  // + kk*1024
  int* flagsG = flags + G * (16 * 32);

  float hold[4] = {0.f, 0.f, 0.f, 0.f};
  float xr_[4], xz_[4], xn_[4];

#pragma unroll
  for (int i = 0; i < 4; ++i) {
    int b = hf * 32 + mt * 16 + l4 * 4 + i;
    size_t xo = ((size_t)(a * S_ + 0) * B_ + b) * H_ + nc;
    unsigned prz = xprz[xo];
    xr_[i] = bf2f((unsigned short)(prz & 0xffff));
    xz_[i] = bf2f((unsigned short)(prz >> 16));
    xn_[i] = xn_arr[xo];
  }

  const f32x4 zero4 = {0.f, 0.f, 0.f, 0.f};

  for (int s = 0; s < S_; ++s) {
    const unsigned short* hprev = (s & 1) ? hbuf0 : hbuf1;
    unsigned short*       hcur  = (s & 1) ? hbuf1 : hbuf0;

    U2 hh[16];
#pragma unroll
    for (int kk = 0; kk < 16; ++kk) {
      unsigned long long* p = (unsigned long long*)(hprev + hbase + kk * 1024);
      hh[kk].u[0] = __hip_atomic_load(p,     __ATOMIC_RELAXED, __HIP_MEMORY_SCOPE_AGENT);
      hh[kk].u[1] = __hip_atomic_load(p + 1, __ATOMIC_RELAXED, __HIP_MEMORY_SCOPE_AGENT);
    }
    f32x4 aR = zero4, aZ = zero4, aHN = zero4;
#pragma unroll
    for (int kk = 0; kk < 16; ++kk) {
      s16x8 bR = __builtin_bit_cast(s16x8, wflat[kk * 128        + nt * 64 + lane]);
      s16x8 bZ = __builtin_bit_cast(s16x8, wflat[2048 + kk * 128 + nt * 64 + lane]);
      s16x8 bN = __builtin_bit_cast(s16x8, wflat[4096 + kk * 128 + nt * 64 + lane]);
      aR  = __builtin_amdgcn_mfma_f32_16x16x32_bf16(hh[kk].v, bR, aR, 0, 0, 0);
      aZ  = __builtin_amdgcn_mfma_f32_16x16x32_bf16(hh[kk].v, bZ, aZ, 0, 0, 0);
      aHN = __builtin_amdgcn_mfma_f32_16x16x32_bf16(hh[kk].v, bN, aHN, 0, 0, 0);
    }

    float hn4[4];
#pragma unroll
    for (int i = 0; i < 4; ++i) {
      float rg = sigm(xr_[i] + aR[i]);
      float zg = sigm(xz_[i] + aZ[i]);
      float ng = tanh_f(xn_[i] + rg * (aHN[i] + vbnh));
      hn4[i] = (1.f - zg) * ng + zg * hold[i];
      hold[i] = hn4[i];
    }

#pragma unroll
    for (int i = 0; i < 4; ++i) {
      int r = mt * 16 + l4 * 4 + i;
      unsigned short nb = f2bf(hn4[i]);
      unsigned other = __shfl_xor((unsigned)nb, 1);
      if ((lane & 1) == 0) {
        unsigned val = (unsigned)nb | (other << 16);
        __hip_atomic_store((unsigned*)(hcur + halfb + (nc >> 3) * 256 + r * 8 + (nc & 6)),
                           val, __ATOMIC_RELAXED, __HIP_MEMORY_SCOPE_AGENT);
      }
    }
    __syncthreads();
    asm volatile("" ::: "memory");
    if (tid == 0)
      __hip_atomic_store(flagsG + slice * 32, s + 1,
                         __ATOMIC_RELAXED, __HIP_MEMORY_SCOPE_AGENT);

#pragma unroll
    for (int i = 0; i < 4; ++i) {
      int b = hf * 32 + mt * 16 + l4 * 4 + i;
      out[((size_t)(a * B_ + b) * S_ + s) * H_ + nc] = hn4[i];
    }
    if (s == S_ - 1) {
#pragma unroll
      for (int i = 0; i < 4; ++i) {
        int b = hf * 32 + mt * 16 + l4 * 4 + i;
        hlast[(size_t)(a * B_ + b) * H_ + nc] = hn4[i];
      }
    } else {
#pragma unroll
      for (int i = 0; i < 4; ++i) {
        int b = hf * 32 + mt * 16 + l4 * 4 + i;
        size_t xo = ((size_t)(a * S_ + (s + 1)) * B_ + b) * H_ + nc;
        unsigned prz = xprz[xo];
        xr_[i] = bf2f((unsigned short)(prz & 0xffff));
        xz_[i] = bf2f((unsigned short)(prz >> 16));
        xn_[i] = xn_arr[xo];
      }
      const int target = s + 1;
      for (;;) {
        int v = __hip_atomic_load(flagsG + (lane & 15) * 32,
                                  __ATOMIC_RELAXED, __HIP_MEMORY_SCOPE_AGENT);
        if (__all(v >= target)) break;
      }
      asm volatile("" ::: "memory");
    }
  }
}

// ---------------------------------------------------------------------------
// Fallback: round-2 persistent kernel (needs only ~1 MB ws).
// ---------------------------------------------------------------------------
__global__ __launch_bounds__(256, 1) void gru_persist(
    const float* __restrict__ x,
    const float* __restrict__ wri, const float* __restrict__ wzi, const float* __restrict__ wni,
    const float* __restrict__ wrh, const float* __restrict__ wzh, const float* __restrict__ wnh,
    const float* __restrict__ bri, const float* __restrict__ bzi, const float* __restrict__ bni,
    const float* __restrict__ brh, const float* __restrict__ bzh, const float* __restrict__ bnh,
    float* __restrict__ out, float* __restrict__ hlast,
    unsigned short* __restrict__ hbuf0, unsigned short* __restrict__ hbuf1,
    int* __restrict__ flags)
{
  __shared__ uint4 wflat[6144];
  const int wg = blockIdx.x, a = wg >> 5, slice = wg & 31, n0 = slice << 4;
  const int tid = threadIdx.x, lane = tid & 63, wid = tid >> 6;
  const int l15 = lane & 15, l4 = lane >> 4, b0w = wid << 4;

  for (int idx = tid; idx < 6144; idx += 256) {
    int set = idx / 3072, rem = idx - set * 3072, gate = rem >> 10;
    int rem2 = rem & 1023, kk = rem2 >> 6, l = rem2 & 63;
    int c = l & 15, kbase = kk * 32 + (l >> 4) * 8;
    const float* W = (set == 0) ? (gate == 0 ? wri : gate == 1 ? wzi : wni)
                                : (gate == 0 ? wrh : gate == 1 ? wzh : wnh);
    const float* wp = W + ((size_t)(a * 512 + kbase)) * 512 + n0 + c;
    PK pk;
#pragma unroll
    for (int j = 0; j < 8; ++j) pk.h[j] = f2bf(wp[(size_t)j * 512]);
    wflat[idx] = pk.u;
  }
  __syncthreads();

  const int nc = n0 + l15;
  const float vbri = bri[a*512+nc], vbzi = bzi[a*512+nc], vbni = bni[a*512+nc];
  const float vbrh = brh[a*512+nc], vbzh = bzh[a*512+nc], vbnh = bnh[a*512+nc];
  const float* xrow = x + (size_t)(a * 64 + b0w + l15) * 65536 + l4 * 8;
  const int hbase = ((a * 64 + l4) * 64 + b0w + l15) * 8;
  int* flagsA = flags + a * 64;
  const f32x4 zero4 = {0.f, 0.f, 0.f, 0.f};
  f32x4 aR, aZ, aXN, aHN;

  auto xpart = [&](int sv) {
    const float* xp = xrow + (size_t)sv * 512;
    aR = zero4; aZ = zero4; aXN = zero4;
#pragma unroll
    for (int kk = 0; kk < 16; ++kk) {
      float4 x0 = *reinterpret_cast<const float4*>(xp + kk * 32);
      float4 x1 = *reinterpret_cast<const float4*>(xp + kk * 32 + 4);
      PH af;
      af.h[0]=f2bf(x0.x); af.h[1]=f2bf(x0.y); af.h[2]=f2bf(x0.z); af.h[3]=f2bf(x0.w);
      af.h[4]=f2bf(x1.x); af.h[5]=f2bf(x1.y); af.h[6]=f2bf(x1.z); af.h[7]=f2bf(x1.w);
      s16x8 bR = __builtin_bit_cast(s16x8, wflat[(kk)*64+lane]);
      s16x8 bZ = __builtin_bit_cast(s16x8, wflat[(16+kk)*64+lane]);
      s16x8 bN = __builtin_bit_cast(s16x8, wflat[(32+kk)*64+lane]);
      aR  = __builtin_amdgcn_mfma_f32_16x16x32_bf16(af.v, bR, aR, 0,0,0);
      aZ  = __builtin_amdgcn_mfma_f32_16x16x32_bf16(af.v, bZ, aZ, 0,0,0);
      aXN = __builtin_amdgcn_mfma_f32_16x16x32_bf16(af.v, bN, aXN, 0,0,0);
    }
  };

  xpart(0);
  for (int s = 0; s < S_; ++s) {
    const unsigned short* hprev = (s & 1) ? hbuf0 : hbuf1;
    unsigned short*       hcur  = (s & 1) ? hbuf1 : hbuf0;
    aHN = zero4;
#pragma unroll
    for (int kk = 0; kk < 16; ++kk) {
      unsigned long long* p = (unsigned long long*)(hprev + hbase + kk * 2048);
      U2 uu;
      uu.u[0] = __hip_atomic_load(p,   __ATOMIC_RELAXED, __HIP_MEMORY_SCOPE_AGENT);
      uu.u[1] = __hip_atomic_load(p+1, __ATOMIC_RELAXED, __HIP_MEMORY_SCOPE_AGENT);
      s16x8 bR = __builtin_bit_cast(s16x8, wflat[(48+kk)*64+lane]);
      s16x8 bZ = __builtin_bit_cast(s16x8, wflat[(64+kk)*64+lane]);
      s16x8 bN = __builtin_bit_cast(s16x8, wflat[(80+kk)*64+lane]);
      aR  = __builtin_amdgcn_mfma_f32_16x16x32_bf16(uu.v, bR, aR, 0,0,0);
      aZ  = __builtin_amdgcn_mfma_f32_16x16x32_bf16(uu.v, bZ, aZ, 0,0,0);
      aHN = __builtin_amdgcn_mfma_f32_16x16x32_bf16(uu.v, bN, aHN, 0,0,0);
    }
#pragma unroll
    for (int i = 0; i < 4; ++i) {
      int r = b0w + l4 * 4 + i;
      unsigned* hop = (unsigned*)(hprev + ((a*64 + (nc>>3))*64 + r)*8 + (nc&6));
      unsigned pair = __hip_atomic_load(hop, __ATOMIC_RELAXED, __HIP_MEMORY_SCOPE_AGENT);
      float hold = bf2f((nc & 1) ? (unsigned short)(pair >> 16) : (unsigned short)(pair & 0xffff));
      float rg = sigm(aR[i] + vbri + vbrh);
      float zg = sigm(aZ[i] + vbzi + vbzh);
      float ng = tanh_f(aXN[i] + vbni + rg * (aHN[i] + vbnh));
      float hnew = (1.f - zg) * ng + zg * hold;
      out[((size_t)(a*64 + r)*128 + s)*512 + nc] = hnew;
      if (s == S_ - 1) hlast[(size_t)(a*64 + r)*512 + nc] = hnew;
      unsigned short nb = f2bf(hnew);
      unsigned other = __shfl_xor((unsigned)nb, 1);
      if ((lane & 1) == 0) {
        unsigned val = (unsigned)nb | (other << 16);
        __hip_atomic_store((unsigned*)(hcur + ((a*64 + (nc>>3))*64 + r)*8 + (nc&6)),
                           val, __ATOMIC_RELAXED, __HIP_MEMORY_SCOPE_AGENT);
      }
    }
    __syncthreads();
    if (tid == 0)
      __hip_atomic_store(flagsA + slice, s + 1, __ATOMIC_RELEASE, __HIP_MEMORY_SCOPE_AGENT);
    if (s < S_ - 1) {
      xpart(s + 1);
      const int target = s + 1;
      for (;;) {
        int v = __hip_atomic_load(flagsA + (lane & 31), __ATOMIC_ACQUIRE, __HIP_MEMORY_SCOPE_AGENT);
        if (__all(v >= target)) break;
        __builtin_amdgcn_s_sleep(1);
      }
    }
  }
}

extern "C" void kernel_launch(void* const* d_in, const int* in_sizes, int n_in,
                              void* d_out, int out_size, void* d_ws, size_t ws_size,
                              hipStream_t stream)
{
  const float* x   = (const float*)d_in[0];
  const float* wri = (const float*)d_in[1];
  const float* wzi = (const float*)d_in[2];
  const float* wni = (const float*)d_in[3];
  const float* wrh = (const float*)d_in[4];
  const float* wzh = (const float*)d_in[5];
  const float* wnh = (const float*)d_in[6];
  const float* bri = (const float*)d_in[7];
  const float* bzi = (const float*)d_in[8];
  const float* bni = (const float*)d_in[9];
  const float* brh = (const float*)d_in[10];
  const float* bzh = (const float*)d_in[11];
  const float* bnh = (const float*)d_in[12];

  float* out   = (float*)d_out;                    // (A,B,S,H)
  float* hlast = out + (size_t)A_ * B_ * S_ * H_;  // (A,B,H)

  const size_t XPRZ  = (size_t)A_ * S_ * B_ * H_;            // u32 / f32 elems
  const size_t HBUF  = (size_t)A_ * 64 * 64 * 8;             // bf16 elems
  const size_t FLAGS_B = (size_t)16 * 16 * 32 * sizeof(int); // 32 KB
  const size_t need_new = XPRZ * 4 * 2 + HBUF * 2 * 2 + FLAGS_B;
  const size_t need_old = HBUF * 2 * 2 + 2048;

  if (ws_size >= need_new) {
    unsigned* xprz = (unsigned*)d_ws;
    float* xn_arr  = (float*)((char*)d_ws + XPRZ * 4);
    unsigned short* hbuf0 = (unsigned short*)((char*)d_ws + XPRZ * 8);
    unsigned short* hbuf1 = hbuf0 + HBUF;
    int* flags = (int*)(hbuf1 + HBUF);
    hipMemsetAsync(hbuf0, 0, HBUF * 2 * 2 + FLAGS_B, stream);
    gru_proj<<<dim3(64, 8, 8), 256, 0, stream>>>(x, wri, wzi, wni,
                                                 bri, bzi, bni, brh, bzh,
                                                 xprz, xn_arr);
    gru_scan<<<256, 256, 0, stream>>>(xprz, xn_arr, wrh, wzh, wnh, bnh,
                                      out, hlast, hbuf0, hbuf1, flags);
  } else if (ws_size >= need_old) {
    unsigned short* hbuf0 = (unsigned short*)d_ws;
    unsigned short* hbuf1 = hbuf0 + HBUF;
    int* flags = (int*)(hbuf1 + HBUF);
    hipMemsetAsync(d_ws, 0, need_old, stream);
    gru_persist<<<256, 256, 0, stream>>>(x, wri, wzi, wni, wrh, wzh, wnh,
                                         bri, bzi, bni, brh, bzh, bnh,
                                         out, hlast, hbuf0, hbuf1, flags);
  }
}